// Round 1
// baseline (723.455 us; speedup 1.0000x reference)
//
#include <hip/hip_runtime.h>
#include <stdint.h>

#define NF 64
#define ND 128
#define NPAIR 2016      // 64*63/2
#define THREADS 256
#define NB 8            // batches per block, double-buffered LDS

typedef __attribute__((ext_vector_type(4))) float  f32x4;
typedef __attribute__((ext_vector_type(16))) float f32x16;
typedef __attribute__((ext_vector_type(4))) short  s16x4;
typedef __attribute__((ext_vector_type(8))) short  s16x8;

// fp32 -> bf16 round-to-nearest-even
__device__ __forceinline__ short f2bf(float v) {
    union { float f; unsigned u; } c; c.f = v;
    unsigned u = c.u;
    u += 0x7fffu + ((u >> 16) & 1u);
    return (short)(u >> 16);
}

// NB batches per WG, double-buffered 2 x 16 KiB LDS (32 KiB total).
// Pipeline per batch i (T14 issue-early/write-late):
//   issue global loads for batch i+1  -> VGPRs       (latency hidden under compute)
//   compute tiles of batch i from lds[cur] (waves 0-2) + store
//   cvt + LDS-write batch i+1 into lds[cur^1]
//   __syncthreads()   (one barrier per batch)
// launch_bounds(256,4): 128-VGPR cap (est. ~80 used, no spill);
// LDS allows 4-5 WGs/CU = 16-20 waves/CU, ample for BW-latency product.
__global__ __launch_bounds__(THREADS, 4) void dotint_kernel(
    const float* __restrict__ x, float* __restrict__ out, int nbatch)
{
    __shared__ short lds[2][NF * ND];   // 2 x 8192 bf16 = 32 KiB

    const int t = threadIdx.x;
    const long long b0 = (long long)blockIdx.x * NB;

    const int wave = t >> 6;
    const int lane = t & 63;
    const int lr   = lane & 31;   // row-in-tile for A/B frag, col for C
    const int lh   = lane >> 5;   // k-half selector
    const int I = wave >> 1;          // 0,0,1  (wave 3: stage-only helper)
    const int J = (wave + 1) >> 1;    // 0,1,1

    // staging LDS offsets: chunk = row*16 + (kc ^ (row&15)), 8 B per s16x4.
    // XOR swizzle keeps both staging writes and fragment reads bank-uniform.
    int soff[8];
    #pragma unroll
    for (int k = 0; k < 8; ++k) {
        const int f    = t + THREADS * k;
        const int row  = f >> 5;            // 32 float4 per row
        const int k4   = f & 31;
        const int kc   = k4 >> 1;
        const int half = k4 & 1;
        soff[k] = (row * 16 + (kc ^ (row & 15))) * 8 + half * 4;
    }

    // ---------------- prologue: stage batch b0 into buffer 0 ----------------
    {
        const f32x4* xg = (const f32x4*)x + b0 * (NF * ND / 4);
        f32x4 v[8];
        #pragma unroll
        for (int k = 0; k < 8; ++k) v[k] = xg[t + THREADS * k];
        #pragma unroll
        for (int k = 0; k < 8; ++k) {
            s16x4 p;
            p[0] = f2bf(v[k][0]); p[1] = f2bf(v[k][1]);
            p[2] = f2bf(v[k][2]); p[3] = f2bf(v[k][3]);
            *(s16x4*)&lds[0][soff[k]] = p;
        }
    }
    __syncthreads();

    // ---------------- main pipeline ----------------
    #pragma unroll 2
    for (int i = 0; i < NB; ++i) {
        const int cur = i & 1;
        const long long g = b0 + i;
        const bool pre = (i + 1 < NB) && (g + 1 < (long long)nbatch);

        // 1) issue next batch's global loads early (hidden under compute)
        f32x4 v[8];
        if (pre) {
            const f32x4* xg = (const f32x4*)x + (g + 1) * (NF * ND / 4);
            #pragma unroll
            for (int k = 0; k < 8; ++k) v[k] = xg[t + THREADS * k];
        }

        // 2) compute gram tiles of current batch from lds[cur]
        //    tiles: wave0 (0,0), wave1 (0,1), wave2 (1,1)
        if (wave < 3 && g < (long long)nbatch) {
            f32x16 acc;
            #pragma unroll
            for (int r = 0; r < 16; ++r) acc[r] = 0.0f;

            #pragma unroll
            for (int kb = 0; kb < 8; ++kb) {
                const int sw = (kb * 2 + lh) ^ (lr & 15);  // (row&15)==(lr&15)
                s16x8 a  = *(const s16x8*)&lds[cur][((I * 32 + lr) * 16 + sw) * 8];
                s16x8 bb = (I == J) ? a
                         : *(const s16x8*)&lds[cur][((J * 32 + lr) * 16 + sw) * 8];
                acc = __builtin_amdgcn_mfma_f32_32x32x16_bf16(a, bb, acc, 0, 0, 0);
            }

            // epilogue: C layout col=lane&31, row=(reg&3)+8*(reg>>2)+4*(lane>>5)
            const long long ob = g * (long long)NPAIR;
            #pragma unroll
            for (int r = 0; r < 16; ++r) {
                const int rowInTile = (r & 3) + 8 * (r >> 2) + 4 * lh;
                const int ii = I * 32 + rowInTile;
                const int jj = J * 32 + lr;
                if (jj > ii) {
                    const int tri = ii * (127 - ii) / 2 + (jj - ii - 1);
                    out[ob + tri] = acc[r];
                }
            }
        }

        // 3) convert + LDS-write next batch into the other buffer
        //    (safe: lds[cur^1] readers all passed the barrier at end of iter i-1)
        if (pre) {
            #pragma unroll
            for (int k = 0; k < 8; ++k) {
                s16x4 p;
                p[0] = f2bf(v[k][0]); p[1] = f2bf(v[k][1]);
                p[2] = f2bf(v[k][2]); p[3] = f2bf(v[k][3]);
                *(s16x4*)&lds[cur ^ 1][soff[k]] = p;
            }
        }
        __syncthreads();
    }
}

extern "C" void kernel_launch(void* const* d_in, const int* in_sizes, int n_in,
                              void* d_out, int out_size, void* d_ws, size_t ws_size,
                              hipStream_t stream) {
    const float* x = (const float*)d_in[0];
    float* out = (float*)d_out;
    const int B = in_sizes[0] / (NF * ND);   // 16384
    const int grid = (B + NB - 1) / NB;      // 2048
    dim3 g(grid), blk(THREADS);
    hipLaunchKernelGGL(dotint_kernel, g, blk, 0, stream, x, out, B);
}